// Round 7
// baseline (1258.887 us; speedup 1.0000x reference)
//
#include <hip/hip_runtime.h>

// Sqrtm via the reference's coupled iteration, B=256, D=256, iterN=5.
// Round 12: LDS eliminated. The symmetry trick (C = A@B^T == A@B, both
// operands read as [outer][k] rows) means the global layout IS the MFMA
// fragment layout: each lane's fragment is a contiguous 16-B global read at
// row*256 + kt + quad*8. A wave's fragment load touches 16 cache lines --
// the SAME count as the staged-copy path -- so L2 request efficiency is
// unchanged, but now there is no stage->vmcnt(0)->barrier lockstep: waves
// run barrier-free with a named two-set register double-buffer (static
// indexing, rule #20), keeping ~16KB/wave in flight DURING the MFMAs.
// Round-11's measured winners kept: XCD-pinned block mapping (FETCH 162->67
// MB, m157/m192), chain schedule, 2-term bf16 planes.
// T-step 1.5*W fold reverts to direct global reads of W in the epilogue
// (same values the LDS fold read; L2-hot under pinning).
//
// Storage: fp32 emulated as 2-term bf16 planes (hi+lo), product via 3 MFMA:
//   A@B ~= Ah@Bh + Al@Bh + Ah@Bl
//
// Chain (A planes live in d_out, dead before the final fp32 overwrite):
//   Z1 = 1.5I - 0.5A
//   3x:  W = A@Z ; T = 1.5W - 0.5(Z@W) ; Z' = T@Z
//   fin: W = A@Z ; T = 1.5W - 0.5(Z@W) [A=Z,B=W] ; out = sqrt(normA)*(T@W)

#define DD 256
#define PLN 65536   // shorts per bf16 plane
#define MATN 65536  // floats per fp32 matrix

typedef short s16x8 __attribute__((ext_vector_type(8)));
typedef short s16x4 __attribute__((ext_vector_type(4)));
typedef float f32x4 __attribute__((ext_vector_type(4)));

__device__ __forceinline__ short bf16rtn(float f) {
    unsigned u = __float_as_uint(f);
    u += 0x7FFFu + ((u >> 16) & 1u);   // round-to-nearest-even
    return (short)(u >> 16);
}
__device__ __forceinline__ float bf16tof(short h) {
    return __uint_as_float(((unsigned)(unsigned short)h) << 16);
}

// ---- setup: sc[lb]=sqrt(normA); X planes = split(invN*x); Z1 planes ----
__global__ __launch_bounds__(256) void setup_kernel(
    const float* __restrict__ x,
    short* __restrict__ zbase, int zstride,
    short* __restrict__ xbase, int xstride,
    float* __restrict__ sc)
{
    const int lb = blockIdx.x, tid = threadIdx.x;
    const float* X = x + (size_t)lb * MATN;
    short* Zh = zbase + (size_t)lb * zstride;  short* Zl = Zh + PLN;
    short* Xh = xbase + (size_t)lb * xstride;  short* Xl = Xh + PLN;
    __shared__ float red[4];
    __shared__ float sInv;

    float s = 0.f;
    for (int i = 0; i < 64; ++i) {
        const float4 v = *(const float4*)(X + ((i * 256 + tid) << 2));
        s += v.x + v.y + v.z + v.w;
    }
    for (int o = 32; o; o >>= 1) s += __shfl_down(s, o, 64);
    if ((tid & 63) == 0) red[tid >> 6] = s;
    __syncthreads();
    if (tid == 0) {
        const float t = red[0] + red[1] + red[2] + red[3];
        sc[lb] = sqrtf(t);
        sInv = 1.f / t;
    }
    __syncthreads();
    const float invN = sInv;

    for (int i = 0; i < 64; ++i) {
        const int e = (i * 256 + tid) << 2;
        const int r = e >> 8, c = e & 255;
        const float4 v = *(const float4*)(X + e);
        const float a0 = invN * v.x, a1 = invN * v.y,
                    a2 = invN * v.z, a3 = invN * v.w;
        s16x4 xh, xl, zh, zl;
        xh[0] = bf16rtn(a0); xl[0] = bf16rtn(a0 - bf16tof(xh[0]));
        xh[1] = bf16rtn(a1); xl[1] = bf16rtn(a1 - bf16tof(xh[1]));
        xh[2] = bf16rtn(a2); xl[2] = bf16rtn(a2 - bf16tof(xh[2]));
        xh[3] = bf16rtn(a3); xl[3] = bf16rtn(a3 - bf16tof(xh[3]));
        const float z0 = ((r == c + 0) ? 1.5f : 0.f) - 0.5f * a0;
        const float z1 = ((r == c + 1) ? 1.5f : 0.f) - 0.5f * a1;
        const float z2 = ((r == c + 2) ? 1.5f : 0.f) - 0.5f * a2;
        const float z3 = ((r == c + 3) ? 1.5f : 0.f) - 0.5f * a3;
        zh[0] = bf16rtn(z0); zl[0] = bf16rtn(z0 - bf16tof(zh[0]));
        zh[1] = bf16rtn(z1); zl[1] = bf16rtn(z1 - bf16tof(zh[1]));
        zh[2] = bf16rtn(z2); zl[2] = bf16rtn(z2 - bf16tof(zh[2]));
        zh[3] = bf16rtn(z3); zl[3] = bf16rtn(z3 - bf16tof(zh[3]));
        *(s16x4*)(Xh + e) = xh; *(s16x4*)(Xl + e) = xl;
        *(s16x4*)(Zh + e) = zh; *(s16x4*)(Zl + e) = zl;
    }
}

// ---- batched GEMM, no LDS: C = alpha*(A@B) [+ 1.5*Aux in epilogue].
// Both operands read as rows (C = A@B^T, valid by symmetry).
// grid = 4*n blocks; XCD-pinned mapping when swz (n%8==0):
//   xcd = bid&7, s = bid>>3, lb = xcd*(n/8) + s/4, tile = s&3.
__global__ __launch_bounds__(256, 2) void gemm_ns(
    const short* Ahg, int astride,
    const short* Bhg, int bstride,
    short* __restrict__ Chg, int cstride,
    float* __restrict__ Cfg, int cfstride,
    const short* Xhg, int xstride,   // aux W planes for the 1.5*W fold
    const float* __restrict__ sc,
    float alpha, int usesc, int nmat, int swz)
{
    const int bid = blockIdx.x;
    int lb, t;
    if (swz) {
        const int xcd = bid & 7, s = bid >> 3;
        lb = xcd * (nmat >> 3) + (s >> 2);
        t = s & 3;
    } else {
        lb = bid >> 2;
        t = bid & 3;
    }
    const int tileR = (t >> 1) << 7, tileC = (t & 1) << 7;
    const int tid = threadIdx.x, lane = tid & 63, wave = tid >> 6;
    const int wr = wave >> 1, wc = wave & 1, ln = lane & 15, quad = lane >> 4;

    const short* Ah = Ahg + (size_t)lb * astride;  const short* Al = Ah + PLN;
    const short* Bh = Bhg + (size_t)lb * bstride;  const short* Bl = Bh + PLN;

    // per-lane fragment row bases (shorts): row*256 + quad*8
    int aRow[4], bRow[4];
#pragma unroll
    for (int i = 0; i < 4; ++i)
        aRow[i] = (tileR + wr * 64 + i * 16 + ln) * DD + quad * 8;
#pragma unroll
    for (int j = 0; j < 4; ++j)
        bRow[j] = (tileC + wc * 64 + j * 16 + ln) * DD + quad * 8;

    f32x4 acc[4][4];
#pragma unroll
    for (int i = 0; i < 4; ++i)
#pragma unroll
        for (int j = 0; j < 4; ++j) {
            acc[i][j][0] = 0.f; acc[i][j][1] = 0.f;
            acc[i][j][2] = 0.f; acc[i][j][3] = 0.f;
        }

    // two named fragment sets (register double-buffer, static indexing)
    s16x8 a0h[4], a0l[4], b0h[4], b0l[4];
    s16x8 a1h[4], a1l[4], b1h[4], b1l[4];

#define LOADSET(AH, AL_, BH, BL_, KT)                                   \
    do {                                                                \
        _Pragma("unroll")                                               \
        for (int i = 0; i < 4; ++i) {                                   \
            AH[i]  = *(const s16x8*)(Ah + aRow[i] + (KT));              \
            AL_[i] = *(const s16x8*)(Al + aRow[i] + (KT));              \
        }                                                               \
        _Pragma("unroll")                                               \
        for (int j = 0; j < 4; ++j) {                                   \
            BH[j]  = *(const s16x8*)(Bh + bRow[j] + (KT));              \
            BL_[j] = *(const s16x8*)(Bl + bRow[j] + (KT));              \
        }                                                               \
    } while (0)

#define MFMASET(AH, AL_, BH, BL_)                                       \
    do {                                                                \
        _Pragma("unroll")                                               \
        for (int j = 0; j < 4; ++j)                                     \
            _Pragma("unroll")                                           \
            for (int i = 0; i < 4; ++i) {                               \
                acc[i][j] = __builtin_amdgcn_mfma_f32_16x16x32_bf16(    \
                    AH[i], BH[j], acc[i][j], 0, 0, 0);                  \
                acc[i][j] = __builtin_amdgcn_mfma_f32_16x16x32_bf16(    \
                    AL_[i], BH[j], acc[i][j], 0, 0, 0);                 \
                acc[i][j] = __builtin_amdgcn_mfma_f32_16x16x32_bf16(    \
                    AH[i], BL_[j], acc[i][j], 0, 0, 0);                 \
            }                                                           \
    } while (0)

    LOADSET(a0h, a0l, b0h, b0l, 0);
#pragma unroll
    for (int kt = 0; kt < DD; kt += 64) {
        LOADSET(a1h, a1l, b1h, b1l, kt + 32);    // issue next while MFMA cur
        MFMASET(a0h, a0l, b0h, b0l);
        if (kt + 64 < DD)
            LOADSET(a0h, a0l, b0h, b0l, kt + 64);
        MFMASET(a1h, a1l, b1h, b1l);
    }
#undef LOADSET
#undef MFMASET

    // Epilogue. C/D layout: col=lane&15, row=quad*4+reg (m89/m91-verified).
    const float alphav = usesc ? sc[lb] : alpha;
    if (Chg) {
        short* Ch = Chg + (size_t)lb * cstride;  short* Cl = Ch + PLN;
        const short* Wh = Xhg ? Xhg + (size_t)lb * xstride : nullptr;
        const short* Wl = Wh ? Wh + PLN : nullptr;
#pragma unroll
        for (int i = 0; i < 4; ++i)
#pragma unroll
            for (int j = 0; j < 4; ++j) {
                const int col = tileC + wc * 64 + j * 16 + ln;
#pragma unroll
                for (int r = 0; r < 4; ++r) {
                    const int row = tileR + wr * 64 + i * 16 + quad * 4 + r;
                    const int idx = row * DD + col;
                    float v = alphav * acc[i][j][r];
                    if (Wh) v = fmaf(1.5f, bf16tof(Wh[idx]) + bf16tof(Wl[idx]), v);
                    const short h = bf16rtn(v);
                    Ch[idx] = h;
                    Cl[idx] = bf16rtn(v - bf16tof(h));
                }
            }
    } else {
        float* Cf = Cfg + (size_t)lb * cfstride;
#pragma unroll
        for (int i = 0; i < 4; ++i)
#pragma unroll
            for (int j = 0; j < 4; ++j) {
                const int col = tileC + wc * 64 + j * 16 + ln;
#pragma unroll
                for (int r = 0; r < 4; ++r) {
                    const int row = tileR + wr * 64 + i * 16 + quad * 4 + r;
                    Cf[row * DD + col] = alphav * acc[i][j][r];
                }
            }
    }
}

extern "C" void kernel_launch(void* const* d_in, const int* in_sizes, int n_in,
                              void* d_out, int out_size, void* d_ws, size_t ws_size,
                              hipStream_t stream)
{
    const float* x = (const float*)d_in[0];
    float* out = (float*)d_out;
    const int NB = 256;

    // ws layout: [512 floats sc/header][nbuf elems x 6 bf16 planes]
    // X planes live in d_out (dead before the final fp32 overwrite).
    float* sc = (float*)d_ws;
    short* base = (short*)(sc + 512);
    long availsh = (long)(ws_size / 2) - 1024;
    int nbuf = (int)(availsh / (6L * PLN));
    if (nbuf > NB) nbuf = NB;
    if (nbuf < 1) nbuf = 1;
    const int ES = 6 * PLN;   // ws element stride (shorts)
    const int EX = 2 * PLN;   // d_out element stride (shorts)

    for (int c0 = 0; c0 < NB; c0 += nbuf) {
        const int n = (NB - c0 < nbuf) ? (NB - c0) : nbuf;
        const int swz = (n % 8 == 0) ? 1 : 0;
        const float* xs = x + (size_t)c0 * MATN;
        float* os = out + (size_t)c0 * MATN;
        short* XH = (short*)os;
        short* SA = base;
        short* SB = base + 2 * PLN;
        short* TT = base + 4 * PLN;
        const dim3 G(4 * n), T(256);

        setup_kernel<<<n, 256, 0, stream>>>(xs, SA, ES, XH, EX, sc);

#define GEMM_B(AH, AS, BH, BS, CH, AXH, AL) \
        gemm_ns<<<G, T, 0, stream>>>((AH), (AS), (BH), (BS), (CH), ES, \
                                     nullptr, 0, (AXH), ES, sc, (AL), 0, n, swz)

        // it1 (Z in SA)
        GEMM_B(XH, EX, SA, ES, SB, nullptr, 1.f);   // W = A@Z -> SB
        GEMM_B(SA, ES, SB, ES, TT, SB, -0.5f);      // T = 1.5W-0.5(Z@W)
        GEMM_B(TT, ES, SA, ES, SB, nullptr, 1.f);   // Z' = T@Z -> SB
        // it2 (Z in SB)
        GEMM_B(XH, EX, SB, ES, SA, nullptr, 1.f);
        GEMM_B(SB, ES, SA, ES, TT, SA, -0.5f);
        GEMM_B(TT, ES, SB, ES, SA, nullptr, 1.f);
        // it3 (Z in SA)
        GEMM_B(XH, EX, SA, ES, SB, nullptr, 1.f);
        GEMM_B(SA, ES, SB, ES, TT, SB, -0.5f);
        GEMM_B(TT, ES, SA, ES, SB, nullptr, 1.f);
        // final (Z in SB)
        GEMM_B(XH, EX, SB, ES, SA, nullptr, 1.f);   // W = Y -> SA
        // final T-step as A=Z(SB), B=W(SA): W@Z == Z@W (polys in A commute),
        // aux = W(SA) so the fold adds 1.5*W.
        GEMM_B(SB, ES, SA, ES, TT, SA, -0.5f);      // T = 1.5W-0.5(Z@W)
        gemm_ns<<<G, T, 0, stream>>>(TT, ES, SA, ES, nullptr, 0, os, MATN,
                                     nullptr, 0, sc, 0.f, 1, n, swz);  // out
#undef GEMM_B
    }
}

// Round 8
// 745.887 us; speedup vs baseline: 1.6878x; 1.6878x over previous
//
#include <hip/hip_runtime.h>

// Sqrtm via the reference's coupled iteration, B=256, D=256, iterN=5.
// Round 13: revert to round-11 structure (proven 689us; round-12's no-LDS
// register pipeline was de-buffered by the scheduler: VGPR=68 proved no
// fragments stayed in flight). One targeted delta on top of round 11:
//   TRANSPOSED, VECTORIZED EPILOGUE. The C/D fragment layout gives each
//   lane 4 consecutive ROWS at one col -> row-major stores are 128 scalar
//   2-B stores/thread (~33.5M store instrs/dispatch ~= 55us issue time,
//   matching the measured 62us). All products here are symmetric
//   (polynomials in A; T,W commute), so store C TRANSPOSED:
//   plane[col*256+row0] gets an s16x4 (8B) per plane per (i,j), and the
//   final fp32 epilogue becomes float4 stores. 4x fewer store instrs.
// Round-11's measured winners kept: XCD-pinned block mapping (FETCH 162->67
// MB), T-step 1.5*W fold from B-LDS, 2-term bf16 planes, chain schedule.
//
// Storage: fp32 emulated as 2-term bf16 planes (hi+lo), product via 3 MFMA:
//   A@B ~= Ah@Bh + Al@Bh + Ah@Bl
// All iterates are symmetric polynomials in A => C = A@B^T == A@B, so both
// operands are read as [outer][k] rows (no transposition anywhere).
//
// Chain (A planes live in d_out, dead before the final fp32 overwrite):
//   Z1 = 1.5I - 0.5A
//   3x:  W = A@Z ; T = 1.5W - 0.5(Z@W) ; Z' = T@Z
//   fin: W = A@Z ; T = 1.5W - 0.5(Z@W) [A=Z,B=W] ; out = sqrt(normA)*(T@W)

#define DD 256
#define PLN 65536   // shorts per bf16 plane
#define MATN 65536  // floats per fp32 matrix

typedef short s16x8 __attribute__((ext_vector_type(8)));
typedef short s16x4 __attribute__((ext_vector_type(4)));
typedef float f32x4 __attribute__((ext_vector_type(4)));

__device__ __forceinline__ short bf16rtn(float f) {
    unsigned u = __float_as_uint(f);
    u += 0x7FFFu + ((u >> 16) & 1u);   // round-to-nearest-even
    return (short)(u >> 16);
}
__device__ __forceinline__ float bf16tof(short h) {
    return __uint_as_float(((unsigned)(unsigned short)h) << 16);
}

// 16B global -> LDS direct (DMA). LDS dest is wave-uniform base + lane*16.
__device__ __forceinline__ void gload16(const short* g, short* l) {
    __builtin_amdgcn_global_load_lds(
        (const __attribute__((address_space(1))) void*)g,
        (__attribute__((address_space(3))) void*)l, 16, 0, 0);
}

// ---- setup: sc[lb]=sqrt(normA); X planes = split(invN*x); Z1 planes ----
__global__ __launch_bounds__(256) void setup_kernel(
    const float* __restrict__ x,
    short* __restrict__ zbase, int zstride,
    short* __restrict__ xbase, int xstride,
    float* __restrict__ sc)
{
    const int lb = blockIdx.x, tid = threadIdx.x;
    const float* X = x + (size_t)lb * MATN;
    short* Zh = zbase + (size_t)lb * zstride;  short* Zl = Zh + PLN;
    short* Xh = xbase + (size_t)lb * xstride;  short* Xl = Xh + PLN;
    __shared__ float red[4];
    __shared__ float sInv;

    float s = 0.f;
    for (int i = 0; i < 64; ++i) {
        const float4 v = *(const float4*)(X + ((i * 256 + tid) << 2));
        s += v.x + v.y + v.z + v.w;
    }
    for (int o = 32; o; o >>= 1) s += __shfl_down(s, o, 64);
    if ((tid & 63) == 0) red[tid >> 6] = s;
    __syncthreads();
    if (tid == 0) {
        const float t = red[0] + red[1] + red[2] + red[3];
        sc[lb] = sqrtf(t);
        sInv = 1.f / t;
    }
    __syncthreads();
    const float invN = sInv;

    for (int i = 0; i < 64; ++i) {
        const int e = (i * 256 + tid) << 2;
        const int r = e >> 8, c = e & 255;
        const float4 v = *(const float4*)(X + e);
        const float a0 = invN * v.x, a1 = invN * v.y,
                    a2 = invN * v.z, a3 = invN * v.w;
        s16x4 xh, xl, zh, zl;
        xh[0] = bf16rtn(a0); xl[0] = bf16rtn(a0 - bf16tof(xh[0]));
        xh[1] = bf16rtn(a1); xl[1] = bf16rtn(a1 - bf16tof(xh[1]));
        xh[2] = bf16rtn(a2); xl[2] = bf16rtn(a2 - bf16tof(xh[2]));
        xh[3] = bf16rtn(a3); xl[3] = bf16rtn(a3 - bf16tof(xh[3]));
        const float z0 = ((r == c + 0) ? 1.5f : 0.f) - 0.5f * a0;
        const float z1 = ((r == c + 1) ? 1.5f : 0.f) - 0.5f * a1;
        const float z2 = ((r == c + 2) ? 1.5f : 0.f) - 0.5f * a2;
        const float z3 = ((r == c + 3) ? 1.5f : 0.f) - 0.5f * a3;
        zh[0] = bf16rtn(z0); zl[0] = bf16rtn(z0 - bf16tof(zh[0]));
        zh[1] = bf16rtn(z1); zl[1] = bf16rtn(z1 - bf16tof(zh[1]));
        zh[2] = bf16rtn(z2); zl[2] = bf16rtn(z2 - bf16tof(zh[2]));
        zh[3] = bf16rtn(z3); zl[3] = bf16rtn(z3 - bf16tof(zh[3]));
        *(s16x4*)(Xh + e) = xh; *(s16x4*)(Xl + e) = xl;
        *(s16x4*)(Zh + e) = zh; *(s16x4*)(Zl + e) = zl;
    }
}

// ---- batched GEMM: C = alpha*(A@B) [+ 1.5*B folded from LDS if fold].
// Both operands read as rows (C = A@B^T, valid by symmetry).
// grid = 4*n blocks; XCD-pinned mapping when swz (n%8==0):
//   xcd = bid&7, s = bid>>3, lb = xcd*(n/8) + s/4, tile = s&3.
__global__ __launch_bounds__(256) void gemm_ns(
    const short* Ahg, int astride,
    const short* Bhg, int bstride,
    short* __restrict__ Chg, int cstride,
    float* __restrict__ Cfg, int cfstride,
    const float* __restrict__ sc,
    float alpha, int fold, int usesc, int nmat, int swz)
{
    __shared__ __align__(16) short sAh[4096];
    __shared__ __align__(16) short sAl[4096];
    __shared__ __align__(16) short sBh[4096];
    __shared__ __align__(16) short sBl[4096];

    const int bid = blockIdx.x;
    int lb, t;
    if (swz) {
        const int xcd = bid & 7, s = bid >> 3;
        lb = xcd * (nmat >> 3) + (s >> 2);
        t = s & 3;
    } else {
        lb = bid >> 2;
        t = bid & 3;
    }
    const int tileR = (t >> 1) << 7, tileC = (t & 1) << 7;
    const int tid = threadIdx.x, lane = tid & 63, wave = tid >> 6;
    const int wr = wave >> 1, wc = wave & 1, ln = lane & 15, quad = lane >> 4;

    const short* Ah = Ahg + (size_t)lb * astride;  const short* Al = Ah + PLN;
    const short* Bh = Bhg + (size_t)lb * bstride;  const short* Bl = Bh + PLN;

    // staging coords: 4 threads (16B each) per row
    const int srow = tid >> 2;                       // 0..63
    const int gs = (tid & 3) ^ ((tid >> 3) & 3);     // swizzled source slot
    const size_t aoff0 = (size_t)(tileR + srow) * DD + gs * 8;
    const size_t aoff1 = aoff0 + (size_t)64 * DD;
    const size_t boff0 = (size_t)(tileC + srow) * DD + gs * 8;
    const size_t boff1 = boff0 + (size_t)64 * DD;
    const int ldo0 = wave * 512;                     // shorts, wave-uniform
    const int ldo1 = 2048 + wave * 512;

    f32x4 acc[4][4];
#pragma unroll
    for (int i = 0; i < 4; ++i)
#pragma unroll
        for (int j = 0; j < 4; ++j) {
            acc[i][j][0] = 0.f; acc[i][j][1] = 0.f;
            acc[i][j][2] = 0.f; acc[i][j][3] = 0.f;
        }

    const int fo = ((quad ^ ((ln >> 1) & 3)) << 3);  // swizzled read slot

    for (int kt = 0; kt < DD; kt += 32) {
        __syncthreads();
        gload16(Ah + aoff0 + kt, sAh + ldo0);
        gload16(Ah + aoff1 + kt, sAh + ldo1);
        gload16(Al + aoff0 + kt, sAl + ldo0);
        gload16(Al + aoff1 + kt, sAl + ldo1);
        gload16(Bh + boff0 + kt, sBh + ldo0);
        gload16(Bh + boff1 + kt, sBh + ldo1);
        gload16(Bl + boff0 + kt, sBl + ldo0);
        gload16(Bl + boff1 + kt, sBl + ldo1);
        __syncthreads();

        s16x8 ahf[4], alf[4];
#pragma unroll
        for (int i = 0; i < 4; ++i) {
            const int ro = (wr * 64 + i * 16 + ln) * 32 + fo;
            ahf[i] = *(const s16x8*)(sAh + ro);
            alf[i] = *(const s16x8*)(sAl + ro);
        }
#pragma unroll
        for (int j = 0; j < 4; ++j) {
            const int co = (wc * 64 + j * 16 + ln) * 32 + fo;
            const s16x8 bh = *(const s16x8*)(sBh + co);
            const s16x8 bl = *(const s16x8*)(sBl + co);
#pragma unroll
            for (int i = 0; i < 4; ++i) {
                acc[i][j] = __builtin_amdgcn_mfma_f32_16x16x32_bf16(ahf[i], bh, acc[i][j], 0, 0, 0);
                acc[i][j] = __builtin_amdgcn_mfma_f32_16x16x32_bf16(alf[i], bh, acc[i][j], 0, 0, 0);
                acc[i][j] = __builtin_amdgcn_mfma_f32_16x16x32_bf16(ahf[i], bl, acc[i][j], 0, 0, 0);
            }
        }

        // fold 1.5*W (aux == B operand) while its granules sit in B-LDS:
        // want W[row][col]; LDS B holds W[tileC+nc][kt+kr]; with nc=col-tileC,
        // kr=row-kt this reads W[col][row] == W[row][col] (W symmetric).
        // alpha=-0.5 in fold steps -> add -3*W so alpha*acc carries +1.5*W.
        if (fold) {
            const int base = kt - tileR - wr * 64;   // wave-uniform
            if (0 <= base && base < 64) {
#pragma unroll
                for (int i = 0; i < 4; ++i) {
                    const int lr = i * 16 - base;     // row offset in k-tile
                    if (0 <= lr && lr < 32) {
#pragma unroll
                        for (int j = 0; j < 4; ++j) {
                            const int nc = wc * 64 + j * 16 + ln;
                            // physical slot of kr: (kr>>3) ^ ((nc>>1)&3)
                            const int key = (nc >> 1) & 3;
#pragma unroll
                            for (int r = 0; r < 4; ++r) {
                                const int kr = lr + quad * 4 + r;
                                const int ph = nc * 32
                                    + (((kr >> 3) ^ key) << 3) + (kr & 7);
                                const float w = bf16tof(sBh[ph])
                                              + bf16tof(sBl[ph]);
                                acc[i][j][r] = fmaf(-3.0f, w, acc[i][j][r]);
                            }
                        }
                    }
                }
            }
        }
    }

    // Epilogue, TRANSPOSED + vectorized. C/D layout: col=lane&15,
    // row=quad*4+reg (m89/m91). C is symmetric (poly in A; T,W commute),
    // so store C^T: plane[col*256 + row0..row0+3] <- acc regs 0..3, one
    // s16x4 (8B) per plane per (i,j) instead of 8 scalar 2B stores.
    const float alphav = usesc ? sc[lb] : alpha;
    if (Chg) {
        short* Ch = Chg + (size_t)lb * cstride;  short* Cl = Ch + PLN;
#pragma unroll
        for (int i = 0; i < 4; ++i)
#pragma unroll
            for (int j = 0; j < 4; ++j) {
                const int col = tileC + wc * 64 + j * 16 + ln;
                const int row0 = tileR + wr * 64 + i * 16 + quad * 4;
                s16x4 hv, lv;
#pragma unroll
                for (int r = 0; r < 4; ++r) {
                    const float v = alphav * acc[i][j][r];
                    hv[r] = bf16rtn(v);
                    lv[r] = bf16rtn(v - bf16tof(hv[r]));
                }
                *(s16x4*)(Ch + col * DD + row0) = hv;
                *(s16x4*)(Cl + col * DD + row0) = lv;
            }
    } else {
        float* Cf = Cfg + (size_t)lb * cfstride;
#pragma unroll
        for (int i = 0; i < 4; ++i)
#pragma unroll
            for (int j = 0; j < 4; ++j) {
                const int col = tileC + wc * 64 + j * 16 + ln;
                const int row0 = tileR + wr * 64 + i * 16 + quad * 4;
                f32x4 fv;
#pragma unroll
                for (int r = 0; r < 4; ++r) fv[r] = alphav * acc[i][j][r];
                *(f32x4*)(Cf + col * DD + row0) = fv;   // out^T == out
            }
    }
}

extern "C" void kernel_launch(void* const* d_in, const int* in_sizes, int n_in,
                              void* d_out, int out_size, void* d_ws, size_t ws_size,
                              hipStream_t stream)
{
    const float* x = (const float*)d_in[0];
    float* out = (float*)d_out;
    const int NB = 256;

    // ws layout: [512 floats sc/header][nbuf elems x 6 bf16 planes]
    // X planes live in d_out (dead before the final fp32 overwrite).
    float* sc = (float*)d_ws;
    short* base = (short*)(sc + 512);
    long availsh = (long)(ws_size / 2) - 1024;
    int nbuf = (int)(availsh / (6L * PLN));
    if (nbuf > NB) nbuf = NB;
    if (nbuf < 1) nbuf = 1;
    const int ES = 6 * PLN;   // ws element stride (shorts)
    const int EX = 2 * PLN;   // d_out element stride (shorts)

    for (int c0 = 0; c0 < NB; c0 += nbuf) {
        const int n = (NB - c0 < nbuf) ? (NB - c0) : nbuf;
        const int swz = (n % 8 == 0) ? 1 : 0;
        const float* xs = x + (size_t)c0 * MATN;
        float* os = out + (size_t)c0 * MATN;
        short* XH = (short*)os;
        short* SA = base;
        short* SB = base + 2 * PLN;
        short* TT = base + 4 * PLN;
        const dim3 G(4 * n), T(256);

        setup_kernel<<<n, 256, 0, stream>>>(xs, SA, ES, XH, EX, sc);

#define GEMM_B(AH, AS, BH, BS, CH, AL, FD) \
        gemm_ns<<<G, T, 0, stream>>>((AH), (AS), (BH), (BS), (CH), ES, \
                                     nullptr, 0, sc, (AL), (FD), 0, n, swz)

        // it1 (Z in SA)
        GEMM_B(XH, EX, SA, ES, SB, 1.f, 0);    // W = A@Z -> SB
        GEMM_B(SA, ES, SB, ES, TT, -0.5f, 1);  // T = 1.5W-0.5(Z@W), W folded
        GEMM_B(TT, ES, SA, ES, SB, 1.f, 0);    // Z' = T@Z -> SB
        // it2 (Z in SB)
        GEMM_B(XH, EX, SB, ES, SA, 1.f, 0);
        GEMM_B(SB, ES, SA, ES, TT, -0.5f, 1);
        GEMM_B(TT, ES, SB, ES, SA, 1.f, 0);
        // it3 (Z in SA)
        GEMM_B(XH, EX, SA, ES, SB, 1.f, 0);
        GEMM_B(SA, ES, SB, ES, TT, -0.5f, 1);
        GEMM_B(TT, ES, SA, ES, SB, 1.f, 0);
        // final (Z in SB)
        GEMM_B(XH, EX, SB, ES, SA, 1.f, 0);    // W = Y -> SA
        // final T-step as A=Z(SB), B=W(SA): W@Z == Z@W (polys in A commute),
        // B operand = W so the LDS fold adds 1.5*W.
        GEMM_B(SB, ES, SA, ES, TT, -0.5f, 1);  // T = 1.5W-0.5(Z@W), W folded
        gemm_ns<<<G, T, 0, stream>>>(TT, ES, SA, ES, nullptr, 0, os, MATN,
                                     sc, 0.f, 0, 1, n, swz);  // out = sqrtN*(T@W)
#undef GEMM_B
    }
}